// Round 5
// baseline (709.039 us; speedup 1.0000x reference)
//
#include <hip/hip_runtime.h>

#define NN 1024
#define CC 768
#define OO 768
#define RR 16
#define MM 8192
#define KK (CC*RR)      /* 12288 */
#define BM 64
#define BO 128
#define BK 64
#define KTILES (KK/BK)  /* 192 */
#define KHALF (KTILES/2)/* 96 */

typedef __bf16 bf16x8 __attribute__((ext_vector_type(8)));
typedef __bf16 bf16x4 __attribute__((ext_vector_type(4)));
typedef float  f32x4  __attribute__((ext_vector_type(4)));

// B' fragment layout (unchanged): elem = (ot*192+kt)*8192 + o16*1024 + ks*512 + quad*128 + lrow*8 + j
//   o = ot*128 + o16*16 + lrow ; k-in-tile = ks*32 + quad*8 + j  (k = c*16+r)
__global__ __launch_bounds__(256) void k_prep(const float* __restrict__ w,
                                              const float* __restrict__ coef,
                                              const float* __restrict__ bias,
                                              __bf16* __restrict__ bfrag,
                                              float* __restrict__ bterm,
                                              float* __restrict__ outz) {
    int id = blockIdx.x;
    int t  = threadIdx.x;
    if (id < 1152) {                       // fragment reorder via LDS transpose
        __shared__ __bf16 ls[128 * 72];    // 128 o-rows x 64 (c,r) + pad 8
        int ot = id / 192, kt = id - ot * 192;
        const float* base = w + ((long)(ot * 128) * CC + kt * 4) * RR;
        // read: 8 x coalesced float4 (each o-row = 64 contiguous floats)
#pragma unroll
        for (int s = 0; s < 8; ++s) {
            int f4  = s * 256 + t;          // 0..2047
            int o_l = f4 >> 4;
            int cr4 = f4 & 15;
            float4 v = *(const float4*)(base + (long)o_l * (CC * RR) + cr4 * 4);
            bf16x4 b = {(__bf16)v.x, (__bf16)v.y, (__bf16)v.z, (__bf16)v.w};
            *(bf16x4*)(&ls[o_l * 72 + cr4 * 4]) = b;
        }
        __syncthreads();
        // write: 4 chunks/thread, contiguous 64B per thread -> coalesced
        long dst = ((long)ot * 192 + kt) * 8192;
#pragma unroll
        for (int ci = 0; ci < 4; ++ci) {
            int ch   = t * 4 + ci;          // 0..1023
            int lrow = ch & 15, quad = (ch >> 4) & 3, ks = (ch >> 6) & 1, o16 = ch >> 7;
            int o_l  = o16 * 16 + lrow;
            int cr   = (ks * 2 + (quad >> 1)) * 16 + (quad & 1) * 8;
            bf16x8 v = *(const bf16x8*)(&ls[o_l * 72 + cr]);
            *(bf16x8*)(bfrag + dst + ch * 8) = v;
        }
    } else if (id < 1152 + 3072) {         // bterm[n,o] = coef[n,:]·bias[o,:]
        int i = (id - 1152) * 256 + t;
        int n = i / OO, o = i - n * OO;
        const float4* cp = (const float4*)(coef + n * RR);
        const float4* bp = (const float4*)(bias + o * RR);
        float s = 0.f;
#pragma unroll
        for (int q = 0; q < 4; ++q) {
            float4 c4 = cp[q], b4 = bp[q];
            s += c4.x * b4.x + c4.y * b4.y + c4.z * b4.z + c4.w * b4.w;
        }
        bterm[i] = s;
    } else {                               // zero d_out (6.29M floats)
        long u = ((long)(id - 4224) * 256 + t) * 8;
        float4 z = {0.f, 0.f, 0.f, 0.f};
        *(float4*)(outz + u) = z;
        *(float4*)(outz + u + 4) = z;
    }
}

// ---- GEMM: 64x128 tiles, split-K=2 -> 1536 blocks (6/CU), dbuf-LDS A, global B ----
__global__ __launch_bounds__(256, 6) void k_gemm(const float* __restrict__ x,
                                                 const float* __restrict__ coef,
                                                 const __bf16* __restrict__ bfrag,
                                                 const float* __restrict__ bterm,
                                                 float* __restrict__ out) {
    __shared__ __bf16 lA[2][BM * BK];      // 2 x 8 KB

    const int tid = threadIdx.x;

    // swizzle: id&7 = XCD; per XCD: 6 ot x 2 kh x 16 local mtiles (x-slab L2-local)
    int xcd = blockIdx.x & 7;
    int s   = blockIdx.x >> 3;             // 0..191
    int ot  = s >> 5;                      // 0..5
    int kh  = (s >> 4) & 1;
    int mtl = s & 15;
    int mtile = xcd * 16 + mtl;            // 0..127
    const int m0 = mtile * BM;
    const int kt0 = kh * KHALF, kt1 = kt0 + KHALF;

    // A-build mapping: thread = (row, c-pair h, r-half rh); builds 2 chunks of 8 r's
    const int arow = tid & 63;
    const int h    = (tid >> 6) & 1;
    const int rh   = tid >> 7;
    const int m_g  = m0 + arow;
    const int n_i  = m_g & (NN - 1);
    const float* xrow = x + (long)m_g * CC;

    float cf[8];
    {
        float4 a = *(const float4*)(coef + n_i * RR + rh * 8);
        float4 b = *(const float4*)(coef + n_i * RR + rh * 8 + 4);
        cf[0] = a.x; cf[1] = a.y; cf[2] = a.z; cf[3] = a.w;
        cf[4] = b.x; cf[5] = b.y; cf[6] = b.z; cf[7] = b.w;
    }

    const int lane = tid & 63, wave = tid >> 6;
    const int wm = (wave & 1) * 32, wo = (wave >> 1) * 64;
    const int lrow = lane & 15, quad = lane >> 4;

    const __bf16* Bk = bfrag + ((long)ot * 192 + kt0) * 8192
                     + (wo >> 4) * 1024 + quad * 128 + lrow * 8;

    f32x4 acc[2][4] = {};
    float2 x2 = *(const float2*)(xrow + kt0 * 4 + 2 * h);

#pragma unroll 1
    for (int kt = kt0; kt < kt1; ++kt) {
        // B fragments: 8 coalesced 16B loads (L1/L2-served), drained by barrier
        bf16x8 bfr[2][4];
#pragma unroll
        for (int ks = 0; ks < 2; ++ks)
#pragma unroll
            for (int io = 0; io < 4; ++io)
                bfr[ks][io] = *(const bf16x8*)(Bk + io * 1024 + ks * 512);
        Bk += 8192;

        // x prefetch for next ktile
        float2 x2n = x2;
        if (kt + 1 < kt1) x2n = *(const float2*)(xrow + (kt + 1) * 4 + 2 * h);

        // build A(kt) into lA[kt&1]: 2 chunks (ci), XOR-swizzled
        __bf16* la = &lA[kt & 1][0];
#pragma unroll
        for (int ci = 0; ci < 2; ++ci) {
            float xv = ci ? x2.y : x2.x;
            bf16x8 v;
#pragma unroll
            for (int j = 0; j < 8; ++j) v[j] = (__bf16)(xv * cf[j]);
            int kb = (2 * h + ci) * 2 + rh;
            *(bf16x8*)(&la[arow * BK + ((kb ^ (arow & 7)) * 8)]) = v;
        }
        x2 = x2n;
        __syncthreads();   // single barrier/ktile (dbuf protects kt+1 writes)

        // compute: 2 k-steps x 8 MFMA
#pragma unroll
        for (int ks = 0; ks < 2; ++ks) {
            bf16x8 af[2];
            int kb = ks * 4 + quad;
#pragma unroll
            for (int f = 0; f < 2; ++f) {
                int row = wm + f * 16 + lrow;
                af[f] = *(const bf16x8*)(&la[row * BK + ((kb ^ (row & 7)) * 8)]);
            }
#pragma unroll
            for (int f = 0; f < 2; ++f)
#pragma unroll
                for (int io = 0; io < 4; ++io)
                    acc[f][io] = __builtin_amdgcn_mfma_f32_16x16x32_bf16(
                        af[f], bfr[ks][io], acc[f][io], 0, 0, 0);
        }
    }

    // epilogue: atomic accumulate; kh==0 adds bterm
#pragma unroll
    for (int f = 0; f < 2; ++f) {
#pragma unroll
        for (int io = 0; io < 4; ++io) {
            int o = ot * 128 + wo + io * 16 + lrow;
#pragma unroll
            for (int r = 0; r < 4; ++r) {
                int moff = wm + f * 16 + quad * 4 + r;
                long m = m0 + moff;
                int n = (int)(m & (NN - 1));
                float v = acc[f][io][r];
                if (kh == 0) v += bterm[(long)n * OO + o];
                atomicAdd(&out[m * OO + o], v);
            }
        }
    }
}

// ---- fallback if workspace too small (correctness-only) ----
__global__ void k_naive(const float* __restrict__ x, const float* __restrict__ coef,
                        const float* __restrict__ w, const float* __restrict__ bias,
                        float* __restrict__ out) {
    long i = (long)blockIdx.x * 256 + threadIdx.x;
    if (i >= (long)MM * OO) return;
    int o = (int)(i % OO);
    long m = i / OO;
    int n = (int)(m & (NN - 1));
    float cf[16];
#pragma unroll
    for (int r = 0; r < 16; ++r) cf[r] = coef[n * RR + r];
    const float* xr = x + m * CC;
    const float* wr = w + (long)o * CC * RR;
    float s = 0.f;
    for (int c = 0; c < CC; ++c) {
        float t = 0.f;
#pragma unroll
        for (int r = 0; r < 16; ++r) t += cf[r] * wr[c * RR + r];
        s += xr[c] * t;
    }
    float bs = 0.f;
#pragma unroll
    for (int r = 0; r < 16; ++r) bs += cf[r] * bias[o * RR + r];
    out[i] = s + bs;
}

extern "C" void kernel_launch(void* const* d_in, const int* in_sizes, int n_in,
                              void* d_out, int out_size, void* d_ws, size_t ws_size,
                              hipStream_t stream) {
    const float* x    = (const float*)d_in[0];
    const float* coef = (const float*)d_in[1];
    const float* w    = (const float*)d_in[2];
    const float* bias = (const float*)d_in[3];
    float* out = (float*)d_out;

    const size_t bfrag_bytes = (size_t)OO * KK * sizeof(__bf16);   // 18,874,368
    const size_t bt_bytes    = (size_t)NN * OO * sizeof(float);    //  3,145,728

    if (ws_size >= bfrag_bytes + bt_bytes) {
        __bf16* bfrag = (__bf16*)d_ws;
        float*  btrm  = (float*)((char*)d_ws + bfrag_bytes);
        // 1152 reorder + 3072 bterm + 3072 zero = 7296 blocks
        k_prep<<<7296, 256, 0, stream>>>(w, coef, bias, bfrag, btrm, out);
        k_gemm<<<1536, 256, 0, stream>>>(x, coef, bfrag, btrm, out);
    } else {
        k_naive<<<(int)(((long)MM * OO + 255) / 256), 256, 0, stream>>>(x, coef, w, bias, out);
    }
}

// Round 6
// 285.880 us; speedup vs baseline: 2.4802x; 2.4802x over previous
//
#include <hip/hip_runtime.h>

#define NN 1024
#define CC 768
#define OO 768
#define RR 16
#define MM 8192
#define KK (CC*RR)      /* 12288 */
#define BM 128
#define BO 96
#define BK 64
#define KTILES (KK/BK)  /* 192 */
#define KHALF (KTILES/2)/* 96 */

typedef __bf16 bf16x8 __attribute__((ext_vector_type(8)));
typedef __bf16 bf16x4 __attribute__((ext_vector_type(4)));
typedef float  f32x4  __attribute__((ext_vector_type(4)));

// B' fragment layout, o16-group-major:
//   elem addr = (o16*192 + kt)*1024 + ks*512 + quad*128 + lrow*8 + j
//   o = o16*16 + lrow ; k = kt*64 + ks*32 + quad*8 + j ; k = c*16+r
//   -> c = kt*4 + ks*2 + (quad>>1), r = (quad&1)*8 + j
__global__ __launch_bounds__(256) void k_prep(const float* __restrict__ w,
                                              const float* __restrict__ coef,
                                              const float* __restrict__ bias,
                                              __bf16* __restrict__ bfrag,
                                              float* __restrict__ out) {
    int id = blockIdx.x;
    int t  = threadIdx.x;
    if (id < 2304) {                       // reorder: block = (o16, group of 4 kt)
        __shared__ __bf16 ls[16 * 260];    // 16 o-rows x 256 floats + pad 4
        int o16 = id / 48, ktg = id - (id / 48) * 48;
        // read: coalesced — each o-row contributes 256 contiguous floats
#pragma unroll
        for (int s = 0; s < 4; ++s) {
            int idx = s * 256 + t;         // 0..1023 float4s
            int o_l = idx >> 6, pos = idx & 63;
            float4 v = *(const float4*)(w + (long)(o16 * 16 + o_l) * KK
                                          + ktg * 256 + pos * 4);
            bf16x4 b = {(__bf16)v.x, (__bf16)v.y, (__bf16)v.z, (__bf16)v.w};
            *(bf16x4*)(&ls[o_l * 260 + pos * 4]) = b;
        }
        __syncthreads();
        // write: 2 chunks/thread, consecutive threads -> consecutive 16B (coalesced)
        long dst = (long)(o16 * 192 + ktg * 4) * 1024;
#pragma unroll
        for (int s = 0; s < 2; ++s) {
            int u = s * 256 + t;           // 0..511 = 4 kt x 128 chunks
            int kt_l = u >> 7, ch = u & 127;
            int ks = ch >> 6, quad = (ch >> 4) & 3, lrow = ch & 15;
            int cr = (kt_l * 4 + ks * 2 + (quad >> 1)) * 16 + (quad & 1) * 8;
            bf16x8 v = *(const bf16x8*)(&ls[lrow * 260 + cr]);
            *(bf16x8*)(bfrag + dst + (long)kt_l * 1024 + ch * 8) = v;
        }
    } else {                               // out[b,n,o] = coef[n,:]·bias[o,:] (init)
        int i = (id - 2304) * 256 + t;     // 0..786431
        int n = i / OO, o = i - n * OO;
        const float4* cp = (const float4*)(coef + n * RR);
        const float4* bp = (const float4*)(bias + o * RR);
        float s = 0.f;
#pragma unroll
        for (int q = 0; q < 4; ++q) {
            float4 c4 = cp[q], b4 = bp[q];
            s += c4.x * b4.x + c4.y * b4.y + c4.z * b4.z + c4.w * b4.w;
        }
#pragma unroll
        for (int b = 0; b < 8; ++b)
            out[(long)(b * NN + n) * OO + o] = s;
    }
}

// ---- GEMM: 128x96 tiles, split-K=2 -> 1024 blocks (4/CU even) ----
// ot == XCD: per-XCD B-slab = 96 x 12288 bf16 = 2.25 MB, L2-resident.
__global__ __launch_bounds__(256, 4) void k_gemm(const float* __restrict__ x,
                                                 const float* __restrict__ coef,
                                                 const __bf16* __restrict__ bfrag,
                                                 float* __restrict__ out) {
    __shared__ __bf16 lA[2][BM * BK];      // 2 x 16 KB

    const int tid = threadIdx.x;

    const int ot    = blockIdx.x & 7;      // == XCD
    const int loc   = blockIdx.x >> 3;     // 0..127
    const int kh    = loc & 1;
    const int mtile = loc >> 1;            // 0..63
    const int m0 = mtile * BM;
    const int kt0 = kh * KHALF, kt1 = kt0 + KHALF;

    // A-build mapping (as r4): thread -> (row am, c-pair ahalf)
    const int am     = tid & 127;
    const int ahalf  = tid >> 7;
    const int m_glob = m0 + am;
    const int n_idx  = m_glob & (NN - 1);
    const float* xrow = x + (long)m_glob * CC;

    float cf[16];
#pragma unroll
    for (int r = 0; r < 16; r += 4) {
        float4 t4 = *(const float4*)(coef + n_idx * RR + r);
        cf[r] = t4.x; cf[r + 1] = t4.y; cf[r + 2] = t4.z; cf[r + 3] = t4.w;
    }

    const int lane = tid & 63, wave = tid >> 6;
    const int wm = (wave & 1) * 64, woq = wave >> 1;   // wave-tile 64x48
    const int lrow = lane & 15, quad = lane >> 4;

    // per-lane B pointers, one per io (o16-group); advance 1024 elems per kt
    const __bf16* Bk[3];
#pragma unroll
    for (int io = 0; io < 3; ++io) {
        int o16 = ot * 6 + woq * 3 + io;
        Bk[io] = bfrag + ((long)o16 * 192 + kt0) * 1024 + quad * 128 + lrow * 8;
    }

    f32x4 acc[4][3] = {};
    float2 x2 = *(const float2*)(xrow + kt0 * 4 + 2 * ahalf);

#pragma unroll 1
    for (int kt = kt0; kt < kt1; ++kt) {
        // B fragments: 6 x 16B loads, guaranteed L2-hit (slab pinned per XCD)
        bf16x8 bfr[2][3];
#pragma unroll
        for (int io = 0; io < 3; ++io) {
            bfr[0][io] = *(const bf16x8*)(Bk[io]);
            bfr[1][io] = *(const bf16x8*)(Bk[io] + 512);
            Bk[io] += 1024;
        }

        // x prefetch for next ktile (covers L3 latency)
        float2 x2n = x2;
        if (kt + 1 < kt1) x2n = *(const float2*)(xrow + (kt + 1) * 4 + 2 * ahalf);

        // build A(kt) into lA[kt&1]: 4 XOR-swizzled chunks/thread
        __bf16* la = &lA[kt & 1][0];
#pragma unroll
        for (int ci = 0; ci < 2; ++ci) {
            float xv = ci ? x2.y : x2.x;
            int c_local = 2 * ahalf + ci;
#pragma unroll
            for (int rh = 0; rh < 2; ++rh) {
                bf16x8 v;
#pragma unroll
                for (int j = 0; j < 8; ++j) v[j] = (__bf16)(xv * cf[rh * 8 + j]);
                int kb = c_local * 2 + rh;
                *(bf16x8*)(&la[am * BK + ((kb ^ (am & 7)) * 8)]) = v;
            }
        }
        x2 = x2n;
        __syncthreads();   // single barrier/ktile (dbuf protects kt+1 writes)

        // compute: 2 k-steps x 12 MFMA
#pragma unroll
        for (int ks = 0; ks < 2; ++ks) {
            bf16x8 af[4];
            int kb = ks * 4 + quad;
#pragma unroll
            for (int im = 0; im < 4; ++im) {
                int row = wm + im * 16 + lrow;
                af[im] = *(const bf16x8*)(&la[row * BK + ((kb ^ (row & 7)) * 8)]);
            }
#pragma unroll
            for (int im = 0; im < 4; ++im)
#pragma unroll
                for (int io = 0; io < 3; ++io)
                    acc[im][io] = __builtin_amdgcn_mfma_f32_16x16x32_bf16(
                        af[im], bfr[ks][io], acc[im][io], 0, 0, 0);
        }
    }

    // epilogue: pure atomic accumulate (out pre-initialized to bias term)
#pragma unroll
    for (int im = 0; im < 4; ++im) {
#pragma unroll
        for (int io = 0; io < 3; ++io) {
            int o = ot * BO + woq * 48 + io * 16 + lrow;
#pragma unroll
            for (int r = 0; r < 4; ++r) {
                int moff = wm + im * 16 + quad * 4 + r;
                long m = m0 + moff;
                atomicAdd(&out[m * OO + o], acc[im][io][r]);
            }
        }
    }
}

// ---- fallback if workspace too small (correctness-only) ----
__global__ void k_naive(const float* __restrict__ x, const float* __restrict__ coef,
                        const float* __restrict__ w, const float* __restrict__ bias,
                        float* __restrict__ out) {
    long i = (long)blockIdx.x * 256 + threadIdx.x;
    if (i >= (long)MM * OO) return;
    int o = (int)(i % OO);
    long m = i / OO;
    int n = (int)(m & (NN - 1));
    float cf[16];
#pragma unroll
    for (int r = 0; r < 16; ++r) cf[r] = coef[n * RR + r];
    const float* xr = x + m * CC;
    const float* wr = w + (long)o * CC * RR;
    float s = 0.f;
    for (int c = 0; c < CC; ++c) {
        float t = 0.f;
#pragma unroll
        for (int r = 0; r < 16; ++r) t += cf[r] * wr[c * RR + r];
        s += xr[c] * t;
    }
    float bs = 0.f;
#pragma unroll
    for (int r = 0; r < 16; ++r) bs += cf[r] * bias[o * RR + r];
    out[i] = s + bs;
}

extern "C" void kernel_launch(void* const* d_in, const int* in_sizes, int n_in,
                              void* d_out, int out_size, void* d_ws, size_t ws_size,
                              hipStream_t stream) {
    const float* x    = (const float*)d_in[0];
    const float* coef = (const float*)d_in[1];
    const float* w    = (const float*)d_in[2];
    const float* bias = (const float*)d_in[3];
    float* out = (float*)d_out;

    const size_t bfrag_bytes = (size_t)OO * KK * sizeof(__bf16);   // 18,874,368

    if (ws_size >= bfrag_bytes) {
        __bf16* bfrag = (__bf16*)d_ws;
        // 2304 reorder + 3072 out-init = 5376 blocks
        k_prep<<<5376, 256, 0, stream>>>(w, coef, bias, bfrag, out);
        k_gemm<<<1024, 256, 0, stream>>>(x, coef, bfrag, out);
    } else {
        k_naive<<<(int)(((long)MM * OO + 255) / 256), 256, 0, stream>>>(x, coef, w, bias, out);
    }
}